// Round 1
// baseline (3454.625 us; speedup 1.0000x reference)
//
#include <hip/hip_runtime.h>
#include <math.h>

#define HID 512

// ---------------- CSR build (counting sort by dst) ----------------
__global__ void count_kernel(const int* __restrict__ ei, int E, int N, int* __restrict__ counts) {
  int e = blockIdx.x * blockDim.x + threadIdx.x;
  if (e >= E + N) return;
  int dst = (e < E) ? ei[E + e] : (e - E);
  atomicAdd(&counts[dst], 1);
}

__global__ void scan_kernel(const int* __restrict__ counts, int* __restrict__ row_off,
                            int* __restrict__ cursor, int n) {
  __shared__ int sums[1024];
  int t = threadIdx.x;
  int L = (n + 1023) >> 10;
  int beg = t * L;
  int end = min(beg + L, n);
  int s = 0;
  for (int i = beg; i < end; ++i) s += counts[i];
  sums[t] = s;
  __syncthreads();
  for (int o = 1; o < 1024; o <<= 1) {
    int v = (t >= o) ? sums[t - o] : 0;
    __syncthreads();
    sums[t] += v;
    __syncthreads();
  }
  int run = sums[t] - s;
  for (int i = beg; i < end; ++i) {
    row_off[i] = run;
    cursor[i] = run;
    run += counts[i];
  }
  if (t == 1023) row_off[n] = sums[1023];
}

__global__ void scatter_kernel(const int* __restrict__ ei, int E, int N,
                               int* __restrict__ cursor, int* __restrict__ sorted_src) {
  int e = blockIdx.x * blockDim.x + threadIdx.x;
  if (e >= E + N) return;
  int src, dst;
  if (e < E) { src = ei[e]; dst = ei[E + e]; }
  else       { src = e - E; dst = e - E; }
  int pos = atomicAdd(&cursor[dst], 1);
  sorted_src[pos] = src;
}

// ---------------- fp32 tiled GEMM: out[M,512] = A[M,K] @ W[K,512] + bias ----------------
__global__ __launch_bounds__(256) void gemm_bias_kernel(
    const float* __restrict__ A, const float* __restrict__ W, const float* __restrict__ bias,
    float* __restrict__ out, int M, int K) {
  __shared__ float As[16][68];
  __shared__ float Bs[16][68];
  int t = threadIdx.x;
  int n0 = blockIdx.x * 64;
  int m0 = blockIdx.y * 64;
  int tm = (t >> 4) << 2;   // 0..60
  int tn = (t & 15) << 2;   // 0..60
  int la_m = t >> 2;        // 0..63
  int la_k = (t & 3) << 2;  // 0,4,8,12
  int lb_k = t >> 4;        // 0..15
  int lb_n = (t & 15) << 2; // 0..60
  float acc[4][4] = {};
  for (int k0 = 0; k0 < K; k0 += 16) {
    float4 av = make_float4(0.f, 0.f, 0.f, 0.f);
    if (m0 + la_m < M)
      av = *(const float4*)(A + (size_t)(m0 + la_m) * K + k0 + la_k);
    As[la_k + 0][la_m] = av.x;
    As[la_k + 1][la_m] = av.y;
    As[la_k + 2][la_m] = av.z;
    As[la_k + 3][la_m] = av.w;
    *(float4*)&Bs[lb_k][lb_n] = *(const float4*)(W + (size_t)(k0 + lb_k) * HID + n0 + lb_n);
    __syncthreads();
    #pragma unroll
    for (int kk = 0; kk < 16; ++kk) {
      float af[4], bf[4];
      *(float4*)af = *(const float4*)&As[kk][tm];
      *(float4*)bf = *(const float4*)&Bs[kk][tn];
      #pragma unroll
      for (int i = 0; i < 4; ++i)
        #pragma unroll
        for (int j = 0; j < 4; ++j)
          acc[i][j] = fmaf(af[i], bf[j], acc[i][j]);
    }
    __syncthreads();
  }
  float4 bv = *(const float4*)(bias + n0 + tn);
  #pragma unroll
  for (int i = 0; i < 4; ++i) {
    int m = m0 + tm + i;
    if (m < M) {
      float4 r;
      r.x = acc[i][0] + bv.x;
      r.y = acc[i][1] + bv.y;
      r.z = acc[i][2] + bv.z;
      r.w = acc[i][3] + bv.w;
      *(float4*)(out + (size_t)m * HID + n0 + tn) = r;
    }
  }
}

// ---------------- fused GATv2 aggregation: one wave per dst node ----------------
// lane = g*8 + l ; element j = lane*8 + c  => head = lane>>3 (j/64), channel = j%64
__global__ __launch_bounds__(256) void agg_kernel(
    const float* __restrict__ XL, const float* __restrict__ XR, const float* __restrict__ att,
    const int* __restrict__ row_off, const int* __restrict__ sorted_src,
    float* __restrict__ out, int N) {
  int wave = threadIdx.x >> 6;
  int lane = threadIdx.x & 63;
  int node = blockIdx.x * 4 + wave;
  if (node >= N) return;
  int base = lane * 8;
  float att8[8], xr8[8];
  #pragma unroll
  for (int c = 0; c < 8; ++c) att8[c] = att[base + c];
  const float* xr = XR + (size_t)node * HID + base;
  #pragma unroll
  for (int c = 0; c < 8; ++c) xr8[c] = xr[c];

  int off = row_off[node];
  int dend = row_off[node + 1];

  // pass 1: logits + online softmax stats (per head; uniform within 8-lane group)
  float m_run = -1e30f, l_run = 0.f;
  for (int e = off; e < dend; ++e) {
    int src = sorted_src[e];
    const float* xl = XL + (size_t)src * HID + base;
    float s = 0.f;
    #pragma unroll
    for (int c = 0; c < 8; ++c) {
      float v = xl[c] + xr8[c];
      v = v > 0.f ? v : 0.2f * v;
      s = fmaf(att8[c], v, s);
    }
    s += __shfl_xor(s, 1);
    s += __shfl_xor(s, 2);
    s += __shfl_xor(s, 4);
    float nm = fmaxf(m_run, s);
    l_run = l_run * __expf(m_run - nm) + __expf(s - nm);
    m_run = nm;
  }
  float inv = 1.f / l_run;

  // pass 2: recompute logit, accumulate weighted xl
  float acc[8] = {};
  for (int e = off; e < dend; ++e) {
    int src = sorted_src[e];
    const float* xl = XL + (size_t)src * HID + base;
    float xl8[8];
    #pragma unroll
    for (int c = 0; c < 8; ++c) xl8[c] = xl[c];
    float s = 0.f;
    #pragma unroll
    for (int c = 0; c < 8; ++c) {
      float v = xl8[c] + xr8[c];
      v = v > 0.f ? v : 0.2f * v;
      s = fmaf(att8[c], v, s);
    }
    s += __shfl_xor(s, 1);
    s += __shfl_xor(s, 2);
    s += __shfl_xor(s, 4);
    float w = __expf(s - m_run) * inv;
    #pragma unroll
    for (int c = 0; c < 8; ++c) acc[c] = fmaf(w, xl8[c], acc[c]);
  }
  float* o = out + (size_t)node * HID + base;
  #pragma unroll
  for (int c = 0; c < 8; ++c) o[c] = acc[c];
}

// ---------------- LayerNorm + ELU + optional residual; one wave per row ----------------
__global__ __launch_bounds__(256) void ln_elu_kernel(
    const float* __restrict__ in, const float* __restrict__ bias,
    const float* __restrict__ g, const float* __restrict__ b,
    const float* __restrict__ res, float* __restrict__ out, int N) {
  int wave = threadIdx.x >> 6;
  int lane = threadIdx.x & 63;
  int row = blockIdx.x * 4 + wave;
  if (row >= N) return;
  int base = lane * 8;
  const float* x = in + (size_t)row * HID + base;
  float v[8];
  #pragma unroll
  for (int c = 0; c < 8; ++c) v[c] = x[c] + bias[base + c];
  float s = 0.f;
  #pragma unroll
  for (int c = 0; c < 8; ++c) s += v[c];
  #pragma unroll
  for (int o = 1; o < 64; o <<= 1) s += __shfl_xor(s, o);
  float mu = s * (1.f / 512.f);
  float var = 0.f;
  #pragma unroll
  for (int c = 0; c < 8; ++c) { float d = v[c] - mu; var = fmaf(d, d, var); }
  #pragma unroll
  for (int o = 1; o < 64; o <<= 1) var += __shfl_xor(var, o);
  var *= (1.f / 512.f);
  float rs = rsqrtf(var + 1e-5f);
  float* op = out + (size_t)row * HID + base;
  const float* rp = res ? res + (size_t)row * HID + base : nullptr;
  #pragma unroll
  for (int c = 0; c < 8; ++c) {
    float y = (v[c] - mu) * rs * g[base + c] + b[base + c];
    y = y > 0.f ? y : expm1f(y);
    if (rp) y += rp[c];
    op[c] = y;
  }
}

// ---------------- launch ----------------
extern "C" void kernel_launch(void* const* d_in, const int* in_sizes, int n_in,
                              void* d_out, int out_size, void* d_ws, size_t ws_size,
                              hipStream_t stream) {
  const float* x  = (const float*)d_in[0];
  const int*   ei = (const int*)d_in[1];
  int E = in_sizes[1] / 2;
  int N = out_size / HID;
  int F_IN = in_sizes[0] / N;
  int Etot = E + N;

  const float* Wl[3] = { (const float*)d_in[2],  (const float*)d_in[10], (const float*)d_in[18] };
  const float* Wr[3] = { (const float*)d_in[3],  (const float*)d_in[11], (const float*)d_in[19] };
  const float* bl[3] = { (const float*)d_in[4],  (const float*)d_in[12], (const float*)d_in[20] };
  const float* br[3] = { (const float*)d_in[5],  (const float*)d_in[13], (const float*)d_in[21] };
  const float* at[3] = { (const float*)d_in[6],  (const float*)d_in[14], (const float*)d_in[22] };
  const float* bs[3] = { (const float*)d_in[7],  (const float*)d_in[15], (const float*)d_in[23] };
  const float* gg[3] = { (const float*)d_in[8],  (const float*)d_in[16], (const float*)d_in[24] };
  const float* bb[3] = { (const float*)d_in[9],  (const float*)d_in[17], (const float*)d_in[25] };

  char* ws = (char*)d_ws;
  size_t off = 0;
  auto alloc = [&](size_t bytes) -> void* {
    void* p = ws + off;
    off += (bytes + 255) & ~(size_t)255;
    return p;
  };
  float* bufA = (float*)alloc((size_t)N * HID * 4);
  float* bufB = (float*)alloc((size_t)N * HID * 4);
  float* bufC = (float*)alloc((size_t)N * HID * 4);
  int* counts     = (int*)alloc((size_t)N * 4);
  int* row_off    = (int*)alloc((size_t)(N + 1) * 4);
  int* cursor     = (int*)alloc((size_t)N * 4);
  int* sorted_src = (int*)alloc((size_t)Etot * 4);

  float* out = (float*)d_out;

  // CSR build
  hipMemsetAsync(counts, 0, (size_t)N * 4, stream);
  count_kernel<<<(Etot + 255) / 256, 256, 0, stream>>>(ei, E, N, counts);
  scan_kernel<<<1, 1024, 0, stream>>>(counts, row_off, cursor, N);
  scatter_kernel<<<(Etot + 255) / 256, 256, 0, stream>>>(ei, E, N, cursor, sorted_src);

  dim3 ggrid(HID / 64, (N + 63) / 64);
  int nblk = (N + 3) / 4;

  // layer 1: x[N,F_IN] -> bufC = h1
  gemm_bias_kernel<<<ggrid, 256, 0, stream>>>(x, Wl[0], bl[0], bufA, N, F_IN);
  gemm_bias_kernel<<<ggrid, 256, 0, stream>>>(x, Wr[0], br[0], bufB, N, F_IN);
  agg_kernel<<<nblk, 256, 0, stream>>>(bufA, bufB, at[0], row_off, sorted_src, out, N);
  ln_elu_kernel<<<nblk, 256, 0, stream>>>(out, bs[0], gg[0], bb[0], nullptr, bufC, N);

  // layer 2: bufC -> bufA = h2 (residual bufC)
  gemm_bias_kernel<<<ggrid, 256, 0, stream>>>(bufC, Wl[1], bl[1], bufA, N, HID);
  gemm_bias_kernel<<<ggrid, 256, 0, stream>>>(bufC, Wr[1], br[1], bufB, N, HID);
  agg_kernel<<<nblk, 256, 0, stream>>>(bufA, bufB, at[1], row_off, sorted_src, out, N);
  ln_elu_kernel<<<nblk, 256, 0, stream>>>(out, bs[1], gg[1], bb[1], bufC, bufA, N);

  // layer 3: bufA -> out (residual bufA)
  gemm_bias_kernel<<<ggrid, 256, 0, stream>>>(bufA, Wl[2], bl[2], bufC, N, HID);
  gemm_bias_kernel<<<ggrid, 256, 0, stream>>>(bufA, Wr[2], br[2], bufB, N, HID);
  agg_kernel<<<nblk, 256, 0, stream>>>(bufC, bufB, at[2], row_off, sorted_src, out, N);
  ln_elu_kernel<<<nblk, 256, 0, stream>>>(out, bs[2], gg[2], bb[2], bufA, out, N);
}

// Round 2
// 1167.305 us; speedup vs baseline: 2.9595x; 2.9595x over previous
//
#include <hip/hip_runtime.h>
#include <math.h>
#include <stdint.h>

#define HID 512

typedef __attribute__((ext_vector_type(8))) short short8;
typedef __attribute__((ext_vector_type(4))) float floatx4;

__device__ __forceinline__ short f2bf(float f) {
  union { float f; uint32_t u; } v; v.f = f;
  uint32_t r = v.u + 0x7FFFu + ((v.u >> 16) & 1u);
  return (short)(r >> 16);
}
__device__ __forceinline__ float bf2f(short h) {
  union { float f; uint32_t u; } v; v.u = ((uint32_t)(unsigned short)h) << 16;
  return v.f;
}
__device__ __forceinline__ void gload16(const void* g, void* lds) {
  __builtin_amdgcn_global_load_lds(
      (const __attribute__((address_space(1))) void*)g,
      (__attribute__((address_space(3))) void*)lds, 16, 0, 0);
}

// ---------------- CSR build (counting sort by dst) ----------------
__global__ void count_kernel(const int* __restrict__ ei, int E, int N, int* __restrict__ counts) {
  int e = blockIdx.x * blockDim.x + threadIdx.x;
  if (e >= E + N) return;
  int dst = (e < E) ? ei[E + e] : (e - E);
  atomicAdd(&counts[dst], 1);
}

__global__ void scan_kernel(const int* __restrict__ counts, int* __restrict__ row_off,
                            int* __restrict__ cursor, int n) {
  __shared__ int sums[1024];
  int t = threadIdx.x;
  int L = (n + 1023) >> 10;
  int beg = t * L;
  int end = min(beg + L, n);
  int s = 0;
  for (int i = beg; i < end; ++i) s += counts[i];
  sums[t] = s;
  __syncthreads();
  for (int o = 1; o < 1024; o <<= 1) {
    int v = (t >= o) ? sums[t - o] : 0;
    __syncthreads();
    sums[t] += v;
    __syncthreads();
  }
  int run = sums[t] - s;
  for (int i = beg; i < end; ++i) {
    row_off[i] = run;
    cursor[i] = run;
    run += counts[i];
  }
  if (t == 1023) row_off[n] = sums[1023];
}

__global__ void scatter_kernel(const int* __restrict__ ei, int E, int N,
                               int* __restrict__ cursor, int* __restrict__ sorted_src) {
  int e = blockIdx.x * blockDim.x + threadIdx.x;
  if (e >= E + N) return;
  int src, dst;
  if (e < E) { src = ei[e]; dst = ei[E + e]; }
  else       { src = e - E; dst = e - E; }
  int pos = atomicAdd(&cursor[dst], 1);
  sorted_src[pos] = src;
}

// ---------------- cast kernels: build tiled+swizzled bf16 operands ----------------
// A_t layout: [mt][kt][128 rows][64 k] with elem = row*64 + (k ^ ((row&7)<<3)),
// tile = 8192 shorts (16 KB), so linear global_load_lds lands the swizzled tile in LDS.

// layer-1 input x [N,256] -> At (KT=4)
__global__ void castX_kernel(const float* __restrict__ x, short* __restrict__ At, int N) {
  int tid = blockIdx.x * blockDim.x + threadIdx.x;
  if (tid >= N * 32) return;
  int row = tid >> 5;
  int base = (tid & 31) << 3;        // k in [0,256)
  const float* p = x + (size_t)row * 256 + base;
  short8 v;
  #pragma unroll
  for (int c = 0; c < 8; ++c) v[c] = f2bf(p[c]);
  int mt = row >> 7, rl = row & 127, kt = base >> 6, kl = base & 63;
  int elem = ((mt * 4 + kt) << 13) + rl * 64 + (kl ^ ((rl & 7) << 3));
  *(short8*)&At[elem] = v;
}

// weights: Wl,Wr [K,512] -> Wt tiled [8 ntiles][KT][128][64], n<512 => Wl col, else Wr
__global__ void castW_kernel(const float* __restrict__ Wl, const float* __restrict__ Wr,
                             short* __restrict__ Wt, int K) {
  int tid = blockIdx.x * blockDim.x + threadIdx.x;
  if (tid >= K * 1024) return;
  int k = tid >> 10, n = tid & 1023;
  float v = (n < 512) ? Wl[(size_t)k * 512 + n] : Wr[(size_t)k * 512 + (n - 512)];
  int KT = K >> 6;
  int nt = n >> 7, r = n & 127, kt = k >> 6, kl = k & 63;
  Wt[(((size_t)nt * KT + kt) << 13) + r * 64 + (kl ^ ((r & 7) << 3))] = f2bf(v);
}

// ---------------- bf16 MFMA GEMM: XLXR[N,1024] = A[N,K] @ [Wl|Wr] + [bl|br] ----------------
__global__ __launch_bounds__(256) void gemm_mfma_kernel(
    const short* __restrict__ At, const short* __restrict__ Wt,
    const float* __restrict__ bl, const float* __restrict__ br,
    short* __restrict__ XLXR, int N, int KT) {
  __shared__ short As[8192];
  __shared__ short Bs[8192];
  int t = threadIdx.x;
  int lane = t & 63, wid = t >> 6;
  int nb = blockIdx.x, mb = blockIdx.y;
  int wm = (wid >> 1) << 6, wn = (wid & 1) << 6;

  const short* Abase = At + ((size_t)mb * KT << 13);
  const short* Bbase = Wt + ((size_t)nb * KT << 13);

  floatx4 acc[4][4] = {};

  int lr = lane & 15;
  int kq = lane >> 4;
  int xorv = (lr & 7) << 3;

  // prologue stage kt=0
  {
    #pragma unroll
    for (int i = 0; i < 4; ++i) {
      int chunk = i * 256 + t;
      int ub = (i * 256 + (wid << 6)) << 3;  // wave-uniform elem base
      gload16(Abase + chunk * 8, (char*)As + ub * 2);
      gload16(Bbase + chunk * 8, (char*)Bs + ub * 2);
    }
  }

  for (int kt = 0; kt < KT; ++kt) {
    __syncthreads();
    short8 af[2][4], bf[2][4];
    #pragma unroll
    for (int ks = 0; ks < 2; ++ks) {
      int ko = ((ks << 5) + (kq << 3)) ^ xorv;
      #pragma unroll
      for (int f = 0; f < 4; ++f) {
        af[ks][f] = *(const short8*)&As[((wm + (f << 4) + lr) << 6) + ko];
        bf[ks][f] = *(const short8*)&Bs[((wn + (f << 4) + lr) << 6) + ko];
      }
    }
    #pragma unroll
    for (int ks = 0; ks < 2; ++ks)
      #pragma unroll
      for (int i = 0; i < 4; ++i)
        #pragma unroll
        for (int j = 0; j < 4; ++j)
          acc[i][j] = __builtin_amdgcn_mfma_f32_16x16x32_bf16(af[ks][i], bf[ks][j], acc[i][j], 0, 0, 0);
    __syncthreads();
    if (kt + 1 < KT) {
      const short* ga = Abase + ((size_t)(kt + 1) << 13);
      const short* gb = Bbase + ((size_t)(kt + 1) << 13);
      #pragma unroll
      for (int i = 0; i < 4; ++i) {
        int chunk = i * 256 + t;
        int ub = (i * 256 + (wid << 6)) << 3;
        gload16(ga + chunk * 8, (char*)As + ub * 2);
        gload16(gb + chunk * 8, (char*)Bs + ub * 2);
      }
    }
  }

  int crow0 = (mb << 7) + wm + (lane >> 4) * 4;
  int ccol0 = (nb << 7) + wn + lr;
  float bias_f[4];
  #pragma unroll
  for (int j = 0; j < 4; ++j) {
    int c = ccol0 + (j << 4);
    bias_f[j] = (c < 512) ? bl[c] : br[c - 512];
  }
  #pragma unroll
  for (int i = 0; i < 4; ++i) {
    #pragma unroll
    for (int r = 0; r < 4; ++r) {
      int row = crow0 + (i << 4) + r;
      if (row < N) {
        #pragma unroll
        for (int j = 0; j < 4; ++j)
          XLXR[(size_t)row * 1024 + ccol0 + (j << 4)] = f2bf(acc[i][j][r] + bias_f[j]);
      }
    }
  }
}

// ---------------- fused single-pass GATv2 aggregation (online softmax, defer-max) ----------------
__global__ __launch_bounds__(256) void agg_kernel(
    const short* __restrict__ XLXR, const float* __restrict__ att,
    const float* __restrict__ bias,
    const int* __restrict__ row_off, const int* __restrict__ sorted_src,
    float* __restrict__ out, int N) {
  int wave = threadIdx.x >> 6;
  int lane = threadIdx.x & 63;
  int node = blockIdx.x * 4 + wave;
  if (node >= N) return;
  int base = lane << 3;
  float att8[8], xr8[8];
  #pragma unroll
  for (int c = 0; c < 8; ++c) att8[c] = att[base + c];
  short8 xrv = *(const short8*)&XLXR[(size_t)node * 1024 + 512 + base];
  #pragma unroll
  for (int c = 0; c < 8; ++c) xr8[c] = bf2f(xrv[c]);

  int off = row_off[node];
  int dend = row_off[node + 1];

  // first edge (every node has >=1 via self-loop)
  float m, l, acc[8];
  {
    int src = sorted_src[off];
    short8 xv = *(const short8*)&XLXR[(size_t)src * 1024 + base];
    float s = 0.f;
    #pragma unroll
    for (int c = 0; c < 8; ++c) {
      float xl = bf2f(xv[c]);
      acc[c] = xl;
      float v = xl + xr8[c];
      v = v > 0.f ? v : 0.2f * v;
      s = fmaf(att8[c], v, s);
    }
    s += __shfl_xor(s, 1);
    s += __shfl_xor(s, 2);
    s += __shfl_xor(s, 4);
    m = s; l = 1.f;
  }

  for (int e = off + 1; e < dend; ++e) {
    int src = sorted_src[e];
    short8 xv = *(const short8*)&XLXR[(size_t)src * 1024 + base];
    float xl8[8];
    float s = 0.f;
    #pragma unroll
    for (int c = 0; c < 8; ++c) {
      xl8[c] = bf2f(xv[c]);
      float v = xl8[c] + xr8[c];
      v = v > 0.f ? v : 0.2f * v;
      s = fmaf(att8[c], v, s);
    }
    s += __shfl_xor(s, 1);
    s += __shfl_xor(s, 2);
    s += __shfl_xor(s, 4);
    float d = s - m;
    if (d > 8.f) {              // defer-max: rescale only on big jumps
      float sc = __expf(-d);
      l = l * sc + 1.f;
      #pragma unroll
      for (int c = 0; c < 8; ++c) acc[c] = fmaf(acc[c], sc, xl8[c]);
      m = s;
    } else {
      float w = __expf(d);
      l += w;
      #pragma unroll
      for (int c = 0; c < 8; ++c) acc[c] = fmaf(w, xl8[c], acc[c]);
    }
  }
  float inv = 1.f / l;
  float* o = out + (size_t)node * 512 + base;
  #pragma unroll
  for (int c = 0; c < 8; ++c) o[c] = fmaf(acc[c], inv, bias[base + c]);
}

// ---------------- LayerNorm + ELU + residual-from-At, writes next-layer At (and/or final) ----------------
__global__ __launch_bounds__(256) void ln_elu_kernel(
    const float* __restrict__ in, const float* __restrict__ g, const float* __restrict__ b,
    short* __restrict__ At, float* __restrict__ fout, int N, int has_res, int write_at) {
  int wave = threadIdx.x >> 6;
  int lane = threadIdx.x & 63;
  int row = blockIdx.x * 4 + wave;
  if (row >= N) return;
  int base = lane << 3;
  const float* x = in + (size_t)row * 512 + base;
  float v[8];
  #pragma unroll
  for (int c = 0; c < 8; ++c) v[c] = x[c];
  float s = 0.f;
  #pragma unroll
  for (int c = 0; c < 8; ++c) s += v[c];
  #pragma unroll
  for (int o = 1; o < 64; o <<= 1) s += __shfl_xor(s, o);
  float mu = s * (1.f / 512.f);
  float var = 0.f;
  #pragma unroll
  for (int c = 0; c < 8; ++c) { float d = v[c] - mu; var = fmaf(d, d, var); }
  #pragma unroll
  for (int o = 1; o < 64; o <<= 1) var += __shfl_xor(var, o);
  var *= (1.f / 512.f);
  float rs = rsqrtf(var + 1e-5f);

  // At address for this row/lane chunk (KT=8 layout)
  int mt = row >> 7, rl = row & 127, kt = base >> 6, kl = base & 63;
  int elem = ((mt * 8 + kt) << 13) + rl * 64 + (kl ^ ((rl & 7) << 3));

  float res[8] = {};
  if (has_res) {
    short8 rv = *(const short8*)&At[elem];
    #pragma unroll
    for (int c = 0; c < 8; ++c) res[c] = bf2f(rv[c]);
  }
  float y[8];
  #pragma unroll
  for (int c = 0; c < 8; ++c) {
    float t = (v[c] - mu) * rs * g[base + c] + b[base + c];
    t = t > 0.f ? t : expm1f(t);
    y[c] = t + res[c];
  }
  if (write_at) {
    short8 w;
    #pragma unroll
    for (int c = 0; c < 8; ++c) w[c] = f2bf(y[c]);
    *(short8*)&At[elem] = w;
  }
  if (fout) {
    float* o = fout + (size_t)row * 512 + base;
    #pragma unroll
    for (int c = 0; c < 8; ++c) o[c] = y[c];
  }
}

// ---------------- launch ----------------
extern "C" void kernel_launch(void* const* d_in, const int* in_sizes, int n_in,
                              void* d_out, int out_size, void* d_ws, size_t ws_size,
                              hipStream_t stream) {
  const float* x  = (const float*)d_in[0];
  const int*   ei = (const int*)d_in[1];
  int E = in_sizes[1] / 2;
  int N = out_size / HID;
  int Etot = E + N;
  int MT = (N + 127) >> 7;   // 391 row tiles

  const float* Wl[3] = { (const float*)d_in[2],  (const float*)d_in[10], (const float*)d_in[18] };
  const float* Wr[3] = { (const float*)d_in[3],  (const float*)d_in[11], (const float*)d_in[19] };
  const float* bl[3] = { (const float*)d_in[4],  (const float*)d_in[12], (const float*)d_in[20] };
  const float* br[3] = { (const float*)d_in[5],  (const float*)d_in[13], (const float*)d_in[21] };
  const float* at[3] = { (const float*)d_in[6],  (const float*)d_in[14], (const float*)d_in[22] };
  const float* bs[3] = { (const float*)d_in[7],  (const float*)d_in[15], (const float*)d_in[23] };
  const float* gg[3] = { (const float*)d_in[8],  (const float*)d_in[16], (const float*)d_in[24] };
  const float* bb[3] = { (const float*)d_in[9],  (const float*)d_in[17], (const float*)d_in[25] };

  char* ws = (char*)d_ws;
  size_t off = 0;
  auto alloc = [&](size_t bytes) -> void* {
    void* p = ws + off;
    off += (bytes + 255) & ~(size_t)255;
    return p;
  };
  short* At   = (short*)alloc((size_t)MT * 8 * 8192 * 2);   // tiled A, KT up to 8
  short* Wt1  = (short*)alloc((size_t)8 * 4 * 8192 * 2);    // K=256
  short* Wt2  = (short*)alloc((size_t)8 * 8 * 8192 * 2);    // K=512
  short* Wt3  = (short*)alloc((size_t)8 * 8 * 8192 * 2);
  short* XLXR = (short*)alloc((size_t)N * 1024 * 2);
  int* counts     = (int*)alloc((size_t)N * 4);
  int* row_off    = (int*)alloc((size_t)(N + 1) * 4);
  int* cursor     = (int*)alloc((size_t)N * 4);
  int* sorted_src = (int*)alloc((size_t)Etot * 4);

  float* out = (float*)d_out;

  // CSR build
  hipMemsetAsync(counts, 0, (size_t)N * 4, stream);
  count_kernel<<<(Etot + 255) / 256, 256, 0, stream>>>(ei, E, N, counts);
  scan_kernel<<<1, 1024, 0, stream>>>(counts, row_off, cursor, N);
  scatter_kernel<<<(Etot + 255) / 256, 256, 0, stream>>>(ei, E, N, cursor, sorted_src);

  // operand prep
  castX_kernel<<<(N * 32 + 255) / 256, 256, 0, stream>>>(x, At, N);
  castW_kernel<<<(256 * 1024 + 255) / 256, 256, 0, stream>>>(Wl[0], Wr[0], Wt1, 256);
  castW_kernel<<<(512 * 1024 + 255) / 256, 256, 0, stream>>>(Wl[1], Wr[1], Wt2, 512);
  castW_kernel<<<(512 * 1024 + 255) / 256, 256, 0, stream>>>(Wl[2], Wr[2], Wt3, 512);

  dim3 ggrid(8, MT);
  int nblk = (N + 3) / 4;

  // layer 1
  gemm_mfma_kernel<<<ggrid, 256, 0, stream>>>(At, Wt1, bl[0], br[0], XLXR, N, 4);
  agg_kernel<<<nblk, 256, 0, stream>>>(XLXR, at[0], bs[0], row_off, sorted_src, out, N);
  ln_elu_kernel<<<nblk, 256, 0, stream>>>(out, gg[0], bb[0], At, nullptr, N, 0, 1);

  // layer 2
  gemm_mfma_kernel<<<ggrid, 256, 0, stream>>>(At, Wt2, bl[1], br[1], XLXR, N, 8);
  agg_kernel<<<nblk, 256, 0, stream>>>(XLXR, at[1], bs[1], row_off, sorted_src, out, N);
  ln_elu_kernel<<<nblk, 256, 0, stream>>>(out, gg[1], bb[1], At, nullptr, N, 1, 1);

  // layer 3
  gemm_mfma_kernel<<<ggrid, 256, 0, stream>>>(At, Wt3, bl[2], br[2], XLXR, N, 8);
  agg_kernel<<<nblk, 256, 0, stream>>>(XLXR, at[2], bs[2], row_off, sorted_src, out, N);
  ln_elu_kernel<<<nblk, 256, 0, stream>>>(out, gg[2], bb[2], At, out, N, 1, 0);
}

// Round 4
// 836.620 us; speedup vs baseline: 4.1293x; 1.3953x over previous
//
#include <hip/hip_runtime.h>
#include <math.h>
#include <stdint.h>

#define HID 512

typedef __attribute__((ext_vector_type(8))) short short8;
typedef __attribute__((ext_vector_type(4))) float floatx4;

__device__ __forceinline__ short f2bf(float f) {
  union { float f; uint32_t u; } v; v.f = f;
  uint32_t r = v.u + 0x7FFFu + ((v.u >> 16) & 1u);
  return (short)(r >> 16);
}
__device__ __forceinline__ float bf2f(short h) {
  union { float f; uint32_t u; } v; v.u = ((uint32_t)(unsigned short)h) << 16;
  return v.f;
}
__device__ __forceinline__ void gload16(const void* g, void* lds) {
  __builtin_amdgcn_global_load_lds(
      (const __attribute__((address_space(1))) void*)g,
      (__attribute__((address_space(3))) void*)lds, 16, 0, 0);
}

// ---------------- CSR build (counting sort by dst) ----------------
__global__ void count_kernel(const int* __restrict__ ei, int E, int N, int* __restrict__ counts) {
  int e = blockIdx.x * blockDim.x + threadIdx.x;
  if (e >= E + N) return;
  int dst = (e < E) ? ei[E + e] : (e - E);
  atomicAdd(&counts[dst], 1);
}

__global__ void scan_kernel(const int* __restrict__ counts, int* __restrict__ row_off,
                            int* __restrict__ cursor, int n) {
  __shared__ int sums[1024];
  int t = threadIdx.x;
  int L = (n + 1023) >> 10;
  int beg = t * L;
  int end = min(beg + L, n);
  int s = 0;
  for (int i = beg; i < end; ++i) s += counts[i];
  sums[t] = s;
  __syncthreads();
  for (int o = 1; o < 1024; o <<= 1) {
    int v = (t >= o) ? sums[t - o] : 0;
    __syncthreads();
    sums[t] += v;
    __syncthreads();
  }
  int run = sums[t] - s;
  for (int i = beg; i < end; ++i) {
    row_off[i] = run;
    cursor[i] = run;
    run += counts[i];
  }
  if (t == 1023) row_off[n] = sums[1023];
}

__global__ void scatter_kernel(const int* __restrict__ ei, int E, int N,
                               int* __restrict__ cursor, int* __restrict__ sorted_src) {
  int e = blockIdx.x * blockDim.x + threadIdx.x;
  if (e >= E + N) return;
  int src, dst;
  if (e < E) { src = ei[e]; dst = ei[E + e]; }
  else       { src = e - E; dst = e - E; }
  int pos = atomicAdd(&cursor[dst], 1);
  sorted_src[pos] = src;
}

// ---------------- cast kernels: build tiled+swizzled bf16 operands ----------------
// A_t layout: [mt][kt][128 rows][64 k] with elem = row*64 + (k ^ ((row&7)<<3)),
// tile = 8192 shorts (16 KB): linear global_load_lds lands the swizzled tile in LDS.

__global__ void castX_kernel(const float* __restrict__ x, short* __restrict__ At, int N) {
  int tid = blockIdx.x * blockDim.x + threadIdx.x;
  if (tid >= N * 32) return;
  int row = tid >> 5;
  int base = (tid & 31) << 3;        // k in [0,256)
  const float* p = x + (size_t)row * 256 + base;
  short8 v;
  #pragma unroll
  for (int c = 0; c < 8; ++c) v[c] = f2bf(p[c]);
  int mt = row >> 7, rl = row & 127, kt = base >> 6, kl = base & 63;
  int elem = ((mt * 4 + kt) << 13) + rl * 64 + (kl ^ ((rl & 7) << 3));
  *(short8*)&At[elem] = v;
}

__global__ void castW_kernel(const float* __restrict__ Wl, const float* __restrict__ Wr,
                             short* __restrict__ Wt, int K) {
  int tid = blockIdx.x * blockDim.x + threadIdx.x;
  if (tid >= K * 1024) return;
  int k = tid >> 10, n = tid & 1023;
  float v = (n < 512) ? Wl[(size_t)k * 512 + n] : Wr[(size_t)k * 512 + (n - 512)];
  int KT = K >> 6;
  int nt = n >> 7, r = n & 127, kt = k >> 6, kl = k & 63;
  Wt[(((size_t)nt * KT + kt) << 13) + r * 64 + (kl ^ ((r & 7) << 3))] = f2bf(v);
}

// ---------------- bf16 MFMA GEMM: XLXR[N,1024] = A[N,K] @ [Wl|Wr] + [bl|br] ----------------
__global__ __launch_bounds__(256) void gemm_mfma_kernel(
    const short* __restrict__ At, const short* __restrict__ Wt,
    const float* __restrict__ bl, const float* __restrict__ br,
    short* __restrict__ XLXR, int N, int KT) {
  __shared__ short As[8192];
  __shared__ short Bs[8192];
  int t = threadIdx.x;
  int lane = t & 63, wid = t >> 6;
  int nb = blockIdx.x, mb = blockIdx.y;
  int wm = (wid >> 1) << 6, wn = (wid & 1) << 6;

  const short* Abase = At + ((size_t)mb * KT << 13);
  const short* Bbase = Wt + ((size_t)nb * KT << 13);

  floatx4 acc[4][4] = {};

  int lr = lane & 15;
  int kq = lane >> 4;
  int xorv = (lr & 7) << 3;

  {
    #pragma unroll
    for (int i = 0; i < 4; ++i) {
      int chunk = i * 256 + t;
      int ub = (i * 256 + (wid << 6)) << 3;  // wave-uniform elem base
      gload16(Abase + chunk * 8, (char*)As + ub * 2);
      gload16(Bbase + chunk * 8, (char*)Bs + ub * 2);
    }
  }

  for (int kt = 0; kt < KT; ++kt) {
    __syncthreads();
    short8 af[2][4], bf[2][4];
    #pragma unroll
    for (int ks = 0; ks < 2; ++ks) {
      int ko = ((ks << 5) + (kq << 3)) ^ xorv;
      #pragma unroll
      for (int f = 0; f < 4; ++f) {
        af[ks][f] = *(const short8*)&As[((wm + (f << 4) + lr) << 6) + ko];
        bf[ks][f] = *(const short8*)&Bs[((wn + (f << 4) + lr) << 6) + ko];
      }
    }
    #pragma unroll
    for (int ks = 0; ks < 2; ++ks)
      #pragma unroll
      for (int i = 0; i < 4; ++i)
        #pragma unroll
        for (int j = 0; j < 4; ++j)
          acc[i][j] = __builtin_amdgcn_mfma_f32_16x16x32_bf16(af[ks][i], bf[ks][j], acc[i][j], 0, 0, 0);
    __syncthreads();
    if (kt + 1 < KT) {
      const short* ga = Abase + ((size_t)(kt + 1) << 13);
      const short* gb = Bbase + ((size_t)(kt + 1) << 13);
      #pragma unroll
      for (int i = 0; i < 4; ++i) {
        int chunk = i * 256 + t;
        int ub = (i * 256 + (wid << 6)) << 3;
        gload16(ga + chunk * 8, (char*)As + ub * 2);
        gload16(gb + chunk * 8, (char*)Bs + ub * 2);
      }
    }
  }

  int crow0 = (mb << 7) + wm + (lane >> 4) * 4;
  int ccol0 = (nb << 7) + wn + lr;
  float bias_f[4];
  #pragma unroll
  for (int j = 0; j < 4; ++j) {
    int c = ccol0 + (j << 4);
    bias_f[j] = (c < 512) ? bl[c] : br[c - 512];
  }
  #pragma unroll
  for (int i = 0; i < 4; ++i) {
    #pragma unroll
    for (int r = 0; r < 4; ++r) {
      int row = crow0 + (i << 4) + r;
      if (row < N) {
        #pragma unroll
        for (int j = 0; j < 4; ++j)
          XLXR[(size_t)row * 1024 + ccol0 + (j << 4)] = f2bf(acc[i][j][r] + bias_f[j]);
      }
    }
  }
}

// ---------------- fused GATv2 aggregation + LayerNorm + ELU + residual ----------------
// One wave per dst node; wave holds the full 512-elem row (8 per lane).
// Epilogue does LN (wave shfl reduce), ELU, residual read from At, writes next-layer
// At (tiled bf16) and/or final f32 out. Edge loop is software-pipelined (prefetch depth 1).
__global__ __launch_bounds__(256) void agg_ln_kernel(
    const short* __restrict__ XLXR, const float* __restrict__ att,
    const float* __restrict__ bias, const float* __restrict__ g, const float* __restrict__ b,
    const int* __restrict__ row_off, const int* __restrict__ sorted_src,
    short* __restrict__ At, float* __restrict__ fout, int N, int has_res, int write_at) {
  int wave = threadIdx.x >> 6;
  int lane = threadIdx.x & 63;
  int node = blockIdx.x * 4 + wave;
  if (node >= N) return;
  int base = lane << 3;

  float att8[8], xr8[8];
  floatx4 a0 = *(const floatx4*)(att + base);
  floatx4 a1 = *(const floatx4*)(att + base + 4);
  #pragma unroll
  for (int c = 0; c < 4; ++c) { att8[c] = a0[c]; att8[c + 4] = a1[c]; }
  short8 xrv = *(const short8*)&XLXR[(size_t)node * 1024 + 512 + base];
  #pragma unroll
  for (int c = 0; c < 8; ++c) xr8[c] = bf2f(xrv[c]);

  int off = row_off[node];
  int dend = row_off[node + 1];

  float m = -1e30f, l = 0.f;
  float acc[8] = {};

  // software-pipelined edge loop
  short8 xv = *(const short8*)&XLXR[(size_t)sorted_src[off] * 1024 + base];
  for (int e = off; e < dend; ++e) {
    short8 cur = xv;
    if (e + 1 < dend)
      xv = *(const short8*)&XLXR[(size_t)sorted_src[e + 1] * 1024 + base];
    float xl8[8];
    float s = 0.f;
    #pragma unroll
    for (int c = 0; c < 8; ++c) {
      xl8[c] = bf2f(cur[c]);
      float v = xl8[c] + xr8[c];
      v = v > 0.f ? v : 0.2f * v;
      s = fmaf(att8[c], v, s);
    }
    s += __shfl_xor(s, 1);
    s += __shfl_xor(s, 2);
    s += __shfl_xor(s, 4);
    float d = s - m;
    if (d > 8.f) {              // defer-max (T13): rescale only on big jumps
      float sc = __expf(-d);
      l = l * sc + 1.f;
      #pragma unroll
      for (int c = 0; c < 8; ++c) acc[c] = fmaf(acc[c], sc, xl8[c]);
      m = s;
    } else {
      float w = __expf(d);
      l += w;
      #pragma unroll
      for (int c = 0; c < 8; ++c) acc[c] = fmaf(w, xl8[c], acc[c]);
    }
  }
  float inv = 1.f / l;

  // y = agg + bias
  float y[8];
  floatx4 b0 = *(const floatx4*)(bias + base);
  floatx4 b1 = *(const floatx4*)(bias + base + 4);
  #pragma unroll
  for (int c = 0; c < 4; ++c) {
    y[c] = fmaf(acc[c], inv, b0[c]);
    y[c + 4] = fmaf(acc[c + 4], inv, b1[c]);
  }

  // LayerNorm stats across the wave (512 elems)
  float s = 0.f;
  #pragma unroll
  for (int c = 0; c < 8; ++c) s += y[c];
  #pragma unroll
  for (int o = 1; o < 64; o <<= 1) s += __shfl_xor(s, o);
  float mu = s * (1.f / 512.f);
  float var = 0.f;
  #pragma unroll
  for (int c = 0; c < 8; ++c) { float d = y[c] - mu; var = fmaf(d, d, var); }
  #pragma unroll
  for (int o = 1; o < 64; o <<= 1) var += __shfl_xor(var, o);
  var *= (1.f / 512.f);
  float rs = rsqrtf(var + 1e-5f);

  // At address for this row/lane chunk (KT=8 layout)
  int mt = node >> 7, rl = node & 127, kt = base >> 6, kl = base & 63;
  int elem = ((mt * 8 + kt) << 13) + rl * 64 + (kl ^ ((rl & 7) << 3));

  float res[8] = {};
  if (has_res) {
    short8 rv = *(const short8*)&At[elem];
    #pragma unroll
    for (int c = 0; c < 8; ++c) res[c] = bf2f(rv[c]);
  }

  floatx4 g0 = *(const floatx4*)(g + base);
  floatx4 g1 = *(const floatx4*)(g + base + 4);
  floatx4 bb0 = *(const floatx4*)(b + base);
  floatx4 bb1 = *(const floatx4*)(b + base + 4);
  float gz[8], bz[8];
  #pragma unroll
  for (int c = 0; c < 4; ++c) { gz[c] = g0[c]; gz[c + 4] = g1[c]; bz[c] = bb0[c]; bz[c + 4] = bb1[c]; }

  float z[8];
  #pragma unroll
  for (int c = 0; c < 8; ++c) {
    float t = (y[c] - mu) * rs * gz[c] + bz[c];
    t = t > 0.f ? t : __expf(t) - 1.f;   // ELU
    z[c] = t + res[c];
  }
  if (write_at) {
    short8 w;
    #pragma unroll
    for (int c = 0; c < 8; ++c) w[c] = f2bf(z[c]);
    *(short8*)&At[elem] = w;
  }
  if (fout) {
    float* o = fout + (size_t)node * 512 + base;
    floatx4 o0, o1;
    #pragma unroll
    for (int c = 0; c < 4; ++c) { o0[c] = z[c]; o1[c] = z[c + 4]; }
    *(floatx4*)o = o0;
    *(floatx4*)(o + 4) = o1;
  }
}

// ---------------- launch ----------------
extern "C" void kernel_launch(void* const* d_in, const int* in_sizes, int n_in,
                              void* d_out, int out_size, void* d_ws, size_t ws_size,
                              hipStream_t stream) {
  const float* x  = (const float*)d_in[0];
  const int*   ei = (const int*)d_in[1];
  int E = in_sizes[1] / 2;
  int N = out_size / HID;
  int Etot = E + N;
  int MT = (N + 127) >> 7;

  const float* Wl[3] = { (const float*)d_in[2],  (const float*)d_in[10], (const float*)d_in[18] };
  const float* Wr[3] = { (const float*)d_in[3],  (const float*)d_in[11], (const float*)d_in[19] };
  const float* bl[3] = { (const float*)d_in[4],  (const float*)d_in[12], (const float*)d_in[20] };
  const float* br[3] = { (const float*)d_in[5],  (const float*)d_in[13], (const float*)d_in[21] };
  const float* at[3] = { (const float*)d_in[6],  (const float*)d_in[14], (const float*)d_in[22] };
  const float* bs[3] = { (const float*)d_in[7],  (const float*)d_in[15], (const float*)d_in[23] };
  const float* gg[3] = { (const float*)d_in[8],  (const float*)d_in[16], (const float*)d_in[24] };
  const float* bb[3] = { (const float*)d_in[9],  (const float*)d_in[17], (const float*)d_in[25] };

  char* ws = (char*)d_ws;
  size_t off = 0;
  auto alloc = [&](size_t bytes) -> void* {
    void* p = ws + off;
    off += (bytes + 255) & ~(size_t)255;
    return p;
  };
  short* At   = (short*)alloc((size_t)MT * 8 * 8192 * 2);
  short* Wt1  = (short*)alloc((size_t)8 * 4 * 8192 * 2);
  short* Wt2  = (short*)alloc((size_t)8 * 8 * 8192 * 2);
  short* Wt3  = (short*)alloc((size_t)8 * 8 * 8192 * 2);
  short* XLXR = (short*)alloc((size_t)N * 1024 * 2);
  int* counts     = (int*)alloc((size_t)N * 4);
  int* row_off    = (int*)alloc((size_t)(N + 1) * 4);
  int* cursor     = (int*)alloc((size_t)N * 4);
  int* sorted_src = (int*)alloc((size_t)Etot * 4);

  float* out = (float*)d_out;

  hipMemsetAsync(counts, 0, (size_t)N * 4, stream);
  count_kernel<<<(Etot + 255) / 256, 256, 0, stream>>>(ei, E, N, counts);
  scan_kernel<<<1, 1024, 0, stream>>>(counts, row_off, cursor, N);
  scatter_kernel<<<(Etot + 255) / 256, 256, 0, stream>>>(ei, E, N, cursor, sorted_src);

  castX_kernel<<<(N * 32 + 255) / 256, 256, 0, stream>>>(x, At, N);
  castW_kernel<<<(256 * 1024 + 255) / 256, 256, 0, stream>>>(Wl[0], Wr[0], Wt1, 256);
  castW_kernel<<<(512 * 1024 + 255) / 256, 256, 0, stream>>>(Wl[1], Wr[1], Wt2, 512);
  castW_kernel<<<(512 * 1024 + 255) / 256, 256, 0, stream>>>(Wl[2], Wr[2], Wt3, 512);

  dim3 ggrid(8, MT);
  int nblk = (N + 3) / 4;

  // layer 1
  gemm_mfma_kernel<<<ggrid, 256, 0, stream>>>(At, Wt1, bl[0], br[0], XLXR, N, 4);
  agg_ln_kernel<<<nblk, 256, 0, stream>>>(XLXR, at[0], bs[0], gg[0], bb[0],
                                          row_off, sorted_src, At, nullptr, N, 0, 1);
  // layer 2
  gemm_mfma_kernel<<<ggrid, 256, 0, stream>>>(At, Wt2, bl[1], br[1], XLXR, N, 8);
  agg_ln_kernel<<<nblk, 256, 0, stream>>>(XLXR, at[1], bs[1], gg[1], bb[1],
                                          row_off, sorted_src, At, nullptr, N, 1, 1);
  // layer 3
  gemm_mfma_kernel<<<ggrid, 256, 0, stream>>>(At, Wt3, bl[2], br[2], XLXR, N, 8);
  agg_ln_kernel<<<nblk, 256, 0, stream>>>(XLXR, at[2], bs[2], gg[2], bb[2],
                                          row_off, sorted_src, At, out, N, 1, 0);
}

// Round 5
// 746.643 us; speedup vs baseline: 4.6269x; 1.1205x over previous
//
#include <hip/hip_runtime.h>
#include <math.h>
#include <stdint.h>

#define HID 512

typedef __attribute__((ext_vector_type(8))) short short8;
typedef __attribute__((ext_vector_type(4))) float floatx4;

__device__ __forceinline__ short f2bf(float f) {
  union { float f; uint32_t u; } v; v.f = f;
  uint32_t r = v.u + 0x7FFFu + ((v.u >> 16) & 1u);
  return (short)(r >> 16);
}
__device__ __forceinline__ float bf2f(short h) {
  union { float f; uint32_t u; } v; v.u = ((uint32_t)(unsigned short)h) << 16;
  return v.f;
}
__device__ __forceinline__ void gload16(const void* g, void* lds) {
  __builtin_amdgcn_global_load_lds(
      (const __attribute__((address_space(1))) void*)g,
      (__attribute__((address_space(3))) void*)lds, 16, 0, 0);
}

// ---------------- CSR build (counting sort by dst) ----------------
__global__ void count_kernel(const int* __restrict__ ei, int E, int N, int* __restrict__ counts) {
  int e = blockIdx.x * blockDim.x + threadIdx.x;
  if (e >= E + N) return;
  int dst = (e < E) ? ei[E + e] : (e - E);
  atomicAdd(&counts[dst], 1);
}

// 3-pass hierarchical exclusive scan over counts[n] (replaces single-block scan).
// pass 1: per-block (1024 elems) sums
__global__ __launch_bounds__(256) void scan_sums_kernel(
    const int* __restrict__ counts, int* __restrict__ bsums, int n) {
  __shared__ int sums[256];
  int t = threadIdx.x;
  int i0 = blockIdx.x * 1024 + t * 4;
  int s = 0;
  if (i0 + 3 < n) {
    int4 v = *(const int4*)&counts[i0];
    s = v.x + v.y + v.z + v.w;
  } else {
    #pragma unroll
    for (int j = 0; j < 4; ++j) if (i0 + j < n) s += counts[i0 + j];
  }
  sums[t] = s;
  __syncthreads();
  #pragma unroll
  for (int o = 1; o < 256; o <<= 1) {
    int v = (t >= o) ? sums[t - o] : 0;
    __syncthreads();
    sums[t] += v;
    __syncthreads();
  }
  if (t == 255) bsums[blockIdx.x] = sums[255];
}

// pass 2: scan block sums -> exclusive block offsets (in place); write row_off[n]=total
__global__ __launch_bounds__(256) void scan_offs_kernel(
    int* __restrict__ bsums, int* __restrict__ row_off, int nb, int n) {
  __shared__ int sums[256];
  int t = threadIdx.x;
  int s = (t < nb) ? bsums[t] : 0;
  sums[t] = s;
  __syncthreads();
  #pragma unroll
  for (int o = 1; o < 256; o <<= 1) {
    int v = (t >= o) ? sums[t - o] : 0;
    __syncthreads();
    sums[t] += v;
    __syncthreads();
  }
  if (t < nb) bsums[t] = sums[t] - s;
  if (t == 255) row_off[n] = sums[255];
}

// pass 3: recompute local scan, add block offset, write row_off + cursor
__global__ __launch_bounds__(256) void scan_write_kernel(
    const int* __restrict__ counts, const int* __restrict__ bsums,
    int* __restrict__ row_off, int* __restrict__ cursor, int n) {
  __shared__ int sums[256];
  int t = threadIdx.x;
  int i0 = blockIdx.x * 1024 + t * 4;
  int v0 = 0, v1 = 0, v2 = 0, v3 = 0;
  bool full = (i0 + 3 < n);
  if (full) {
    int4 v = *(const int4*)&counts[i0];
    v0 = v.x; v1 = v.y; v2 = v.z; v3 = v.w;
  } else {
    if (i0 < n)     v0 = counts[i0];
    if (i0 + 1 < n) v1 = counts[i0 + 1];
    if (i0 + 2 < n) v2 = counts[i0 + 2];
  }
  int tsum = v0 + v1 + v2 + v3;
  sums[t] = tsum;
  __syncthreads();
  #pragma unroll
  for (int o = 1; o < 256; o <<= 1) {
    int v = (t >= o) ? sums[t - o] : 0;
    __syncthreads();
    sums[t] += v;
    __syncthreads();
  }
  int tex = sums[t] - tsum + bsums[blockIdx.x];
  int4 e;
  e.x = tex;
  e.y = tex + v0;
  e.z = e.y + v1;
  e.w = e.z + v2;
  if (full) {
    *(int4*)&row_off[i0] = e;
    *(int4*)&cursor[i0] = e;
  } else {
    if (i0 < n)     { row_off[i0] = e.x;     cursor[i0] = e.x; }
    if (i0 + 1 < n) { row_off[i0 + 1] = e.y; cursor[i0 + 1] = e.y; }
    if (i0 + 2 < n) { row_off[i0 + 2] = e.z; cursor[i0 + 2] = e.z; }
  }
}

__global__ void scatter_kernel(const int* __restrict__ ei, int E, int N,
                               int* __restrict__ cursor, int* __restrict__ sorted_src) {
  int e = blockIdx.x * blockDim.x + threadIdx.x;
  if (e >= E + N) return;
  int src, dst;
  if (e < E) { src = ei[e]; dst = ei[E + e]; }
  else       { src = e - E; dst = e - E; }
  int pos = atomicAdd(&cursor[dst], 1);
  sorted_src[pos] = src;
}

// ---------------- cast kernels: build tiled+swizzled bf16 operands ----------------
// A_t layout: [mt][kt][128 rows][64 k] with elem = row*64 + (k ^ ((row&7)<<3)),
// tile = 8192 shorts (16 KB): linear global_load_lds lands the swizzled tile in LDS.

__global__ void castX_kernel(const float* __restrict__ x, short* __restrict__ At, int N) {
  int tid = blockIdx.x * blockDim.x + threadIdx.x;
  if (tid >= N * 32) return;
  int row = tid >> 5;
  int base = (tid & 31) << 3;        // k in [0,256)
  const float* p = x + (size_t)row * 256 + base;
  short8 v;
  #pragma unroll
  for (int c = 0; c < 8; ++c) v[c] = f2bf(p[c]);
  int mt = row >> 7, rl = row & 127, kt = base >> 6, kl = base & 63;
  int elem = ((mt * 4 + kt) << 13) + rl * 64 + (kl ^ ((rl & 7) << 3));
  *(short8*)&At[elem] = v;
}

__global__ void castW_kernel(const float* __restrict__ Wl, const float* __restrict__ Wr,
                             short* __restrict__ Wt, int K) {
  int tid = blockIdx.x * blockDim.x + threadIdx.x;
  if (tid >= K * 1024) return;
  int k = tid >> 10, n = tid & 1023;
  float v = (n < 512) ? Wl[(size_t)k * 512 + n] : Wr[(size_t)k * 512 + (n - 512)];
  int KT = K >> 6;
  int nt = n >> 7, r = n & 127, kt = k >> 6, kl = k & 63;
  Wt[(((size_t)nt * KT + kt) << 13) + r * 64 + (kl ^ ((r & 7) << 3))] = f2bf(v);
}

// ---------------- bf16 MFMA GEMM: XLXR[N,1024] = A[N,K] @ [Wl|Wr] + [bl|br] ----------------
__global__ __launch_bounds__(256) void gemm_mfma_kernel(
    const short* __restrict__ At, const short* __restrict__ Wt,
    const float* __restrict__ bl, const float* __restrict__ br,
    short* __restrict__ XLXR, int N, int KT) {
  __shared__ short As[8192];
  __shared__ short Bs[8192];
  int t = threadIdx.x;
  int lane = t & 63, wid = t >> 6;
  int nb = blockIdx.x, mb = blockIdx.y;
  int wm = (wid >> 1) << 6, wn = (wid & 1) << 6;

  const short* Abase = At + ((size_t)mb * KT << 13);
  const short* Bbase = Wt + ((size_t)nb * KT << 13);

  floatx4 acc[4][4] = {};

  int lr = lane & 15;
  int kq = lane >> 4;
  int xorv = (lr & 7) << 3;

  {
    #pragma unroll
    for (int i = 0; i < 4; ++i) {
      int chunk = i * 256 + t;
      int ub = (i * 256 + (wid << 6)) << 3;  // wave-uniform elem base
      gload16(Abase + chunk * 8, (char*)As + ub * 2);
      gload16(Bbase + chunk * 8, (char*)Bs + ub * 2);
    }
  }

  for (int kt = 0; kt < KT; ++kt) {
    __syncthreads();
    short8 af[2][4], bf[2][4];
    #pragma unroll
    for (int ks = 0; ks < 2; ++ks) {
      int ko = ((ks << 5) + (kq << 3)) ^ xorv;
      #pragma unroll
      for (int f = 0; f < 4; ++f) {
        af[ks][f] = *(const short8*)&As[((wm + (f << 4) + lr) << 6) + ko];
        bf[ks][f] = *(const short8*)&Bs[((wn + (f << 4) + lr) << 6) + ko];
      }
    }
    #pragma unroll
    for (int ks = 0; ks < 2; ++ks)
      #pragma unroll
      for (int i = 0; i < 4; ++i)
        #pragma unroll
        for (int j = 0; j < 4; ++j)
          acc[i][j] = __builtin_amdgcn_mfma_f32_16x16x32_bf16(af[ks][i], bf[ks][j], acc[i][j], 0, 0, 0);
    __syncthreads();
    if (kt + 1 < KT) {
      const short* ga = Abase + ((size_t)(kt + 1) << 13);
      const short* gb = Bbase + ((size_t)(kt + 1) << 13);
      #pragma unroll
      for (int i = 0; i < 4; ++i) {
        int chunk = i * 256 + t;
        int ub = (i * 256 + (wid << 6)) << 3;
        gload16(ga + chunk * 8, (char*)As + ub * 2);
        gload16(gb + chunk * 8, (char*)Bs + ub * 2);
      }
    }
  }

  int crow0 = (mb << 7) + wm + (lane >> 4) * 4;
  int ccol0 = (nb << 7) + wn + lr;
  float bias_f[4];
  #pragma unroll
  for (int j = 0; j < 4; ++j) {
    int c = ccol0 + (j << 4);
    bias_f[j] = (c < 512) ? bl[c] : br[c - 512];
  }
  #pragma unroll
  for (int i = 0; i < 4; ++i) {
    #pragma unroll
    for (int r = 0; r < 4; ++r) {
      int row = crow0 + (i << 4) + r;
      if (row < N) {
        #pragma unroll
        for (int j = 0; j < 4; ++j)
          XLXR[(size_t)row * 1024 + ccol0 + (j << 4)] = f2bf(acc[i][j][r] + bias_f[j]);
      }
    }
  }
}

// ---------------- fused GATv2 aggregation + LayerNorm + ELU + residual ----------------
// One wave per dst node; wave holds the full 512-elem row (8 per lane).
// Epilogue does LN (wave shfl reduce), ELU, residual read from At, writes next-layer
// At (tiled bf16) and/or final f32 out. Edge loop is software-pipelined (prefetch depth 1).
__global__ __launch_bounds__(256) void agg_ln_kernel(
    const short* __restrict__ XLXR, const float* __restrict__ att,
    const float* __restrict__ bias, const float* __restrict__ g, const float* __restrict__ b,
    const int* __restrict__ row_off, const int* __restrict__ sorted_src,
    short* __restrict__ At, float* __restrict__ fout, int N, int has_res, int write_at) {
  int wave = threadIdx.x >> 6;
  int lane = threadIdx.x & 63;
  int node = blockIdx.x * 4 + wave;
  if (node >= N) return;
  int base = lane << 3;

  float att8[8], xr8[8];
  floatx4 a0 = *(const floatx4*)(att + base);
  floatx4 a1 = *(const floatx4*)(att + base + 4);
  #pragma unroll
  for (int c = 0; c < 4; ++c) { att8[c] = a0[c]; att8[c + 4] = a1[c]; }
  short8 xrv = *(const short8*)&XLXR[(size_t)node * 1024 + 512 + base];
  #pragma unroll
  for (int c = 0; c < 8; ++c) xr8[c] = bf2f(xrv[c]);

  int off = row_off[node];
  int dend = row_off[node + 1];

  float m = -1e30f, l = 0.f;
  float acc[8] = {};

  // software-pipelined edge loop
  short8 xv = *(const short8*)&XLXR[(size_t)sorted_src[off] * 1024 + base];
  for (int e = off; e < dend; ++e) {
    short8 cur = xv;
    if (e + 1 < dend)
      xv = *(const short8*)&XLXR[(size_t)sorted_src[e + 1] * 1024 + base];
    float xl8[8];
    float s = 0.f;
    #pragma unroll
    for (int c = 0; c < 8; ++c) {
      xl8[c] = bf2f(cur[c]);
      float v = xl8[c] + xr8[c];
      v = v > 0.f ? v : 0.2f * v;
      s = fmaf(att8[c], v, s);
    }
    s += __shfl_xor(s, 1);
    s += __shfl_xor(s, 2);
    s += __shfl_xor(s, 4);
    float d = s - m;
    if (d > 8.f) {              // defer-max (T13): rescale only on big jumps
      float sc = __expf(-d);
      l = l * sc + 1.f;
      #pragma unroll
      for (int c = 0; c < 8; ++c) acc[c] = fmaf(acc[c], sc, xl8[c]);
      m = s;
    } else {
      float w = __expf(d);
      l += w;
      #pragma unroll
      for (int c = 0; c < 8; ++c) acc[c] = fmaf(w, xl8[c], acc[c]);
    }
  }
  float inv = 1.f / l;

  // y = agg + bias
  float y[8];
  floatx4 b0 = *(const floatx4*)(bias + base);
  floatx4 b1 = *(const floatx4*)(bias + base + 4);
  #pragma unroll
  for (int c = 0; c < 4; ++c) {
    y[c] = fmaf(acc[c], inv, b0[c]);
    y[c + 4] = fmaf(acc[c + 4], inv, b1[c]);
  }

  // LayerNorm stats across the wave (512 elems)
  float s = 0.f;
  #pragma unroll
  for (int c = 0; c < 8; ++c) s += y[c];
  #pragma unroll
  for (int o = 1; o < 64; o <<= 1) s += __shfl_xor(s, o);
  float mu = s * (1.f / 512.f);
  float var = 0.f;
  #pragma unroll
  for (int c = 0; c < 8; ++c) { float d = y[c] - mu; var = fmaf(d, d, var); }
  #pragma unroll
  for (int o = 1; o < 64; o <<= 1) var += __shfl_xor(var, o);
  var *= (1.f / 512.f);
  float rs = rsqrtf(var + 1e-5f);

  // At address for this row/lane chunk (KT=8 layout)
  int mt = node >> 7, rl = node & 127, kt = base >> 6, kl = base & 63;
  int elem = ((mt * 8 + kt) << 13) + rl * 64 + (kl ^ ((rl & 7) << 3));

  float res[8] = {};
  if (has_res) {
    short8 rv = *(const short8*)&At[elem];
    #pragma unroll
    for (int c = 0; c < 8; ++c) res[c] = bf2f(rv[c]);
  }

  floatx4 g0 = *(const floatx4*)(g + base);
  floatx4 g1 = *(const floatx4*)(g + base + 4);
  floatx4 bb0 = *(const floatx4*)(b + base);
  floatx4 bb1 = *(const floatx4*)(b + base + 4);
  float gz[8], bz[8];
  #pragma unroll
  for (int c = 0; c < 4; ++c) { gz[c] = g0[c]; gz[c + 4] = g1[c]; bz[c] = bb0[c]; bz[c + 4] = bb1[c]; }

  float z[8];
  #pragma unroll
  for (int c = 0; c < 8; ++c) {
    float t = (y[c] - mu) * rs * gz[c] + bz[c];
    t = t > 0.f ? t : __expf(t) - 1.f;   // ELU
    z[c] = t + res[c];
  }
  if (write_at) {
    short8 w;
    #pragma unroll
    for (int c = 0; c < 8; ++c) w[c] = f2bf(z[c]);
    *(short8*)&At[elem] = w;
  }
  if (fout) {
    float* o = fout + (size_t)node * 512 + base;
    floatx4 o0, o1;
    #pragma unroll
    for (int c = 0; c < 4; ++c) { o0[c] = z[c]; o1[c] = z[c + 4]; }
    *(floatx4*)o = o0;
    *(floatx4*)(o + 4) = o1;
  }
}

// ---------------- launch ----------------
extern "C" void kernel_launch(void* const* d_in, const int* in_sizes, int n_in,
                              void* d_out, int out_size, void* d_ws, size_t ws_size,
                              hipStream_t stream) {
  const float* x  = (const float*)d_in[0];
  const int*   ei = (const int*)d_in[1];
  int E = in_sizes[1] / 2;
  int N = out_size / HID;
  int Etot = E + N;
  int MT = (N + 127) >> 7;
  int NB = (N + 1023) >> 10;   // scan blocks (<=256 requires N<=262144)

  const float* Wl[3] = { (const float*)d_in[2],  (const float*)d_in[10], (const float*)d_in[18] };
  const float* Wr[3] = { (const float*)d_in[3],  (const float*)d_in[11], (const float*)d_in[19] };
  const float* bl[3] = { (const float*)d_in[4],  (const float*)d_in[12], (const float*)d_in[20] };
  const float* br[3] = { (const float*)d_in[5],  (const float*)d_in[13], (const float*)d_in[21] };
  const float* at[3] = { (const float*)d_in[6],  (const float*)d_in[14], (const float*)d_in[22] };
  const float* bs[3] = { (const float*)d_in[7],  (const float*)d_in[15], (const float*)d_in[23] };
  const float* gg[3] = { (const float*)d_in[8],  (const float*)d_in[16], (const float*)d_in[24] };
  const float* bb[3] = { (const float*)d_in[9],  (const float*)d_in[17], (const float*)d_in[25] };

  char* ws = (char*)d_ws;
  size_t off = 0;
  auto alloc = [&](size_t bytes) -> void* {
    void* p = ws + off;
    off += (bytes + 255) & ~(size_t)255;
    return p;
  };
  short* At   = (short*)alloc((size_t)MT * 8 * 8192 * 2);
  short* Wt1  = (short*)alloc((size_t)8 * 4 * 8192 * 2);
  short* Wt2  = (short*)alloc((size_t)8 * 8 * 8192 * 2);
  short* Wt3  = (short*)alloc((size_t)8 * 8 * 8192 * 2);
  short* XLXR = (short*)alloc((size_t)N * 1024 * 2);
  int* counts     = (int*)alloc((size_t)N * 4);
  int* row_off    = (int*)alloc((size_t)(N + 1) * 4);
  int* cursor     = (int*)alloc((size_t)N * 4);
  int* sorted_src = (int*)alloc((size_t)Etot * 4);
  int* bsums      = (int*)alloc((size_t)256 * 4);

  float* out = (float*)d_out;

  // CSR build (parallel 3-pass scan)
  hipMemsetAsync(counts, 0, (size_t)N * 4, stream);
  count_kernel<<<(Etot + 255) / 256, 256, 0, stream>>>(ei, E, N, counts);
  scan_sums_kernel<<<NB, 256, 0, stream>>>(counts, bsums, N);
  scan_offs_kernel<<<1, 256, 0, stream>>>(bsums, row_off, NB, N);
  scan_write_kernel<<<NB, 256, 0, stream>>>(counts, bsums, row_off, cursor, N);
  scatter_kernel<<<(Etot + 255) / 256, 256, 0, stream>>>(ei, E, N, cursor, sorted_src);

  castX_kernel<<<(N * 32 + 255) / 256, 256, 0, stream>>>(x, At, N);
  castW_kernel<<<(256 * 1024 + 255) / 256, 256, 0, stream>>>(Wl[0], Wr[0], Wt1, 256);
  castW_kernel<<<(512 * 1024 + 255) / 256, 256, 0, stream>>>(Wl[1], Wr[1], Wt2, 512);
  castW_kernel<<<(512 * 1024 + 255) / 256, 256, 0, stream>>>(Wl[2], Wr[2], Wt3, 512);

  dim3 ggrid(8, MT);
  int nblk = (N + 3) / 4;

  // layer 1
  gemm_mfma_kernel<<<ggrid, 256, 0, stream>>>(At, Wt1, bl[0], br[0], XLXR, N, 4);
  agg_ln_kernel<<<nblk, 256, 0, stream>>>(XLXR, at[0], bs[0], gg[0], bb[0],
                                          row_off, sorted_src, At, nullptr, N, 0, 1);
  // layer 2
  gemm_mfma_kernel<<<ggrid, 256, 0, stream>>>(At, Wt2, bl[1], br[1], XLXR, N, 8);
  agg_ln_kernel<<<nblk, 256, 0, stream>>>(XLXR, at[1], bs[1], gg[1], bb[1],
                                          row_off, sorted_src, At, nullptr, N, 1, 1);
  // layer 3
  gemm_mfma_kernel<<<ggrid, 256, 0, stream>>>(At, Wt3, bl[2], br[2], XLXR, N, 8);
  agg_ln_kernel<<<nblk, 256, 0, stream>>>(XLXR, at[2], bs[2], gg[2], bb[2],
                                          row_off, sorted_src, At, out, N, 1, 0);
}